// Round 4
// baseline (216.602 us; speedup 1.0000x reference)
//
#include <hip/hip_runtime.h>
#include <math.h>

// Problem constants
#define NB     16384
#define NJOINT 14
#define NCOL   14
#define NPIX   196            // 14*14 == 49 float4 exactly
#define NTASKS (NB * NJOINT)  // 229376
#define RAD    4

#define BLOCK1 128
#define GRID1  (NTASKS / BLOCK1)   // 1792 blocks = exactly 7 per CU on 256 CUs

typedef float f4 __attribute__((ext_vector_type(4)));

__global__ __launch_bounds__(BLOCK1) void mse2_fused(
    const float* __restrict__ osp,     // [B, 2*NJ, 196]
    const float* __restrict__ h,       // [B, NJ, 196]
    const float* __restrict__ t,       // [B, NJ, 2]
    const float* __restrict__ v,       // [B, NJ, 2]
    unsigned int* __restrict__ counter,// ws + 0   (memset to 0 each call)
    double* __restrict__ partials,     // ws + 16  (GRID1*2 doubles)
    float* __restrict__ out)
{
    __shared__ float tbl[NPIX];        // tbl[p*14+o]: 1-D gaussian response, delta at p, output o
    __shared__ float rmax[NCOL];       // row max (row min is exactly 0: support 9 < 14)
    __shared__ double sd[BLOCK1], sn[BLOCK1];
    __shared__ unsigned int s_old;

    const int tid = threadIdx.x;

    // ---- build the 14x14 separable-gaussian table once per block ----
    for (int e = tid; e < NPIX; e += BLOCK1) {
        double kd[2 * RAD + 1];
        double ks = 0.0;
        #pragma unroll
        for (int d = 0; d <= 2 * RAD; ++d) {
            double xx = (double)(d - RAD);
            kd[d] = exp(-0.5 * xx * xx);
            ks += kd[d];
        }
        const int p = e / NCOL, o = e % NCOL;
        float s = 0.f;
        #pragma unroll
        for (int d = 0; d <= 2 * RAD; ++d) {
            int i = o + d;                                     // padded index 0..21
            int m = (i < RAD) ? (RAD - 1 - i)                  // symmetric reflect left
                  : (i < RAD + NCOL) ? (i - RAD)
                  : (2 * (RAD + NCOL) - 1 - i - RAD);          // 31 - i
            if (m == p) s += (float)(kd[d] / ks);
        }
        tbl[p * NCOL + o] = s;
    }
    __syncthreads();
    if (tid < NCOL) {
        float mxv = tbl[tid * NCOL];
        for (int o = 1; o < NCOL; ++o) mxv = fmaxf(mxv, tbl[tid * NCOL + o]);
        rmax[tid] = mxv;
    }
    __syncthreads();

    // ---- one task per thread ----
    const int task = blockIdx.x * BLOCK1 + tid;   // always < NTASKS (exact fit)

    const float2 tv = reinterpret_cast<const float2*>(t)[task];
    const float t0 = tv.x;
    const float t1 = tv.y;
    const float v0 = reinterpret_cast<const float2*>(v)[task].x;
    const bool vis = ((int)v0) == 1;
    const float visf = vis ? 1.f : 0.f;

    // splat center (trunc + clip, matches reference)
    const int xi = min(NCOL - 1, max(0, (int)(t0 * (float)NCOL)));
    const int yi = min(NCOL - 1, max(0, (int)(t1 * (float)NCOL)));
    const float inv = 1.f / (rmax[yi] * rmax[xi]);   // mn == 0 exactly

    // gaussian rows in registers; fold inv + visibility into the x-row
    float gys[NCOL], gxs[NCOL];
    #pragma unroll
    for (int k = 0; k < NCOL; ++k) {
        gys[k] = tbl[yi * NCOL + k];
        gxs[k] = vis ? tbl[xi * NCOL + k] * inv : 0.f;
    }

    const f4* __restrict__ hb4 =
        reinterpret_cast<const f4*>(h + (size_t)task * NPIX);

    float acc  = 0.f;    // d1 partial
    float mval = -1.f;
    int   midx = 0;

    #pragma unroll
    for (int q = 0; q < NPIX / 4; ++q) {
        const f4 hv4 = __builtin_nontemporal_load(&hb4[q]);
        #pragma unroll
        for (int j = 0; j < 4; ++j) {
            const int el = 4 * q + j;            // compile-time constant
            const int y = el / NCOL;             // compile-time
            const int x = el - y * NCOL;         // compile-time
            const float hv = hv4[j];
            // first-occurrence argmax (ascending el)
            if (hv > mval) { mval = hv; midx = el; }
            const float tgt = gys[y] * gxs[x];   // == gn for visible, 0 for invisible
            const float d   = hv - tgt;
            const float c   = d * d;
            // invisible: row 0 of diff zeroed (visf=0); visible: full
            acc += (y == 0) ? visf * c : c;
        }
    }

    // d2 + N contribution (per-thread)
    float d2v = 0.f, nv = 0.f;
    if (vis) {
        nv = v0;   // == 1
        const int yC = midx / NCOL;
        const int xC = midx - yC * NCOL;
        const int b  = task / NJOINT;
        const int j  = task - b * NJOINT;
        const float* __restrict__ ob = osp + ((size_t)b * (2 * NJOINT) + j) * NPIX;
        const float osx = ob[midx];
        const float osy = ob[(size_t)NJOINT * NPIX + midx];
        const bool cond = mval > 0.5f;
        const float sc = 1.0f / (float)NCOL;
        const float x0 = cond ? (osx + (float)xC) * sc : 0.f;
        const float x1 = cond ? (osy + (float)yC) * sc : 0.f;
        const float dx = x0 - t0;
        const float dy = x1 - t1;
        d2v = dx * dx + dy * dy;
    }

    // ---- deterministic block reduction (doubles) ----
    sd[tid] = (double)acc + (double)d2v;
    sn[tid] = (double)nv;
    __syncthreads();
    #pragma unroll
    for (int off = BLOCK1 / 2; off > 0; off >>= 1) {
        if (tid < off) {
            sd[tid] += sd[tid + off];
            sn[tid] += sn[tid + off];
        }
        __syncthreads();
    }
    if (tid == 0) {
        partials[blockIdx.x * 2 + 0] = sd[0];
        partials[blockIdx.x * 2 + 1] = sn[0];
        __threadfence();                       // release partials (device scope)
        s_old = atomicAdd(counter, 1u);        // device-scope RMW
    }
    __syncthreads();

    // ---- last finishing block reduces all partials (fixed order -> deterministic) ----
    if (s_old == GRID1 - 1) {
        __threadfence();                       // acquire: invalidate caches before reading
        double s = 0.0, n = 0.0;
        for (int i = tid; i < GRID1; i += BLOCK1) {
            s += ((volatile const double*)partials)[i * 2 + 0];
            n += ((volatile const double*)partials)[i * 2 + 1];
        }
        sd[tid] = s;
        sn[tid] = n;
        __syncthreads();
        #pragma unroll
        for (int off = BLOCK1 / 2; off > 0; off >>= 1) {
            if (tid < off) {
                sd[tid] += sd[tid + off];
                sn[tid] += sn[tid + off];
            }
            __syncthreads();
        }
        if (tid == 0) out[0] = (float)(sd[0] / sn[0]);
    }
}

extern "C" void kernel_launch(void* const* d_in, const int* in_sizes, int n_in,
                              void* d_out, int out_size, void* d_ws, size_t ws_size,
                              hipStream_t stream) {
    const float* osp = (const float*)d_in[0];
    const float* h   = (const float*)d_in[1];
    // d_in[2] = op, unused by the reference
    const float* t   = (const float*)d_in[3];
    const float* v   = (const float*)d_in[4];

    unsigned int* counter = (unsigned int*)d_ws;
    double* partials = (double*)((char*)d_ws + 16);
    float* out = (float*)d_out;

    // zero the completion counter (graph-capturable memset node)
    hipMemsetAsync(d_ws, 0, 16, stream);
    mse2_fused<<<GRID1, BLOCK1, 0, stream>>>(osp, h, t, v, counter, partials, out);
}

// Round 5
// 42.704 us; speedup vs baseline: 5.0722x; 5.0722x over previous
//
#include <hip/hip_runtime.h>
#include <math.h>

// Problem constants
#define NB     16384
#define NJOINT 14
#define NCOL   14
#define NPIX   196            // 14*14 == 49 float4 exactly
#define NTASKS (NB * NJOINT)  // 229376
#define RAD    4

#define BLOCK1 256
#define GRID1  (NTASKS / BLOCK1)   // 896 blocks

typedef float f4 __attribute__((ext_vector_type(4)));

__global__ __launch_bounds__(BLOCK1) void mse2_main(
    const float* __restrict__ osp,   // [B, 2*NJ, 196]
    const float* __restrict__ h,     // [B, NJ, 196]
    const float* __restrict__ t,     // [B, NJ, 2]
    const float* __restrict__ v,     // [B, NJ, 2]
    double* __restrict__ partials)   // [GRID1*2]
{
    __shared__ float tbl[NPIX];      // tbl[p*14+o]: 1-D gaussian response, delta at p, output o
    __shared__ float rmax[NCOL];     // row max (row min is exactly 0: 9-tap support < 14)
    __shared__ double sd[BLOCK1], sn[BLOCK1];

    const int tid = threadIdx.x;

    // ---- build the 14x14 separable-gaussian table once per block ----
    if (tid < NPIX) {
        // normalized gaussian taps, computed once (double, like reference)
        double kd[2 * RAD + 1];
        double ks = 0.0;
        #pragma unroll
        for (int d = 0; d <= 2 * RAD; ++d) {
            double xx = (double)(d - RAD);
            kd[d] = exp(-0.5 * xx * xx);
            ks += kd[d];
        }
        const int p = tid / NCOL, o = tid % NCOL;
        float s = 0.f;
        #pragma unroll
        for (int d = 0; d <= 2 * RAD; ++d) {
            int i = o + d;                                     // padded index 0..21
            int m = (i < RAD) ? (RAD - 1 - i)                  // symmetric reflect left
                  : (i < RAD + NCOL) ? (i - RAD)
                  : (2 * (RAD + NCOL) - 1 - i - RAD);          // 31 - i
            if (m == p) s += (float)(kd[d] / ks);
        }
        tbl[p * NCOL + o] = s;
    }
    __syncthreads();
    if (tid < NCOL) {
        float mxv = tbl[tid * NCOL];
        for (int o = 1; o < NCOL; ++o) mxv = fmaxf(mxv, tbl[tid * NCOL + o]);
        rmax[tid] = mxv;
    }
    __syncthreads();

    // ---- one task per thread ----
    const int task = blockIdx.x * BLOCK1 + tid;   // always < NTASKS (exact fit)

    const float2 tv = reinterpret_cast<const float2*>(t)[task];
    const float t0 = tv.x;
    const float t1 = tv.y;
    const float v0 = reinterpret_cast<const float2*>(v)[task].x;
    const bool vis = ((int)v0) == 1;
    const float visf = vis ? 1.f : 0.f;

    // splat center (trunc + clip, matches reference)
    const int xi = min(NCOL - 1, max(0, (int)(t0 * (float)NCOL)));
    const int yi = min(NCOL - 1, max(0, (int)(t1 * (float)NCOL)));
    const float inv = 1.f / (rmax[yi] * rmax[xi]);   // min of outer product == 0 exactly

    // gaussian rows in registers; fold inv + visibility into the x-row
    float gys[NCOL], gxs[NCOL];
    #pragma unroll
    for (int k = 0; k < NCOL; ++k) {
        gys[k] = tbl[yi * NCOL + k];
        gxs[k] = vis ? tbl[xi * NCOL + k] * inv : 0.f;
    }

    const f4* __restrict__ hb4 =
        reinterpret_cast<const f4*>(h + (size_t)task * NPIX);

    float acc  = 0.f;    // d1 partial
    float mval = -1.f;
    int   midx = 0;

    #pragma unroll
    for (int q = 0; q < NPIX / 4; ++q) {
        const f4 hv4 = hb4[q];
        #pragma unroll
        for (int j = 0; j < 4; ++j) {
            const int el = 4 * q + j;            // compile-time constant
            const int y = el / NCOL;             // compile-time
            const int x = el - y * NCOL;         // compile-time
            const float hv = hv4[j];
            // first-occurrence argmax (ascending el)
            if (hv > mval) { mval = hv; midx = el; }
            const float tgt = gys[y] * gxs[x];   // == gn (visible) or 0 (invisible)
            const float d   = hv - tgt;
            const float c   = d * d;
            // invisible: row 0 of diff zeroed (visf=0); visible: full
            acc += (y == 0) ? visf * c : c;
        }
    }

    // d2 + N contribution (per-thread)
    float d2v = 0.f, nv = 0.f;
    if (vis) {
        nv = v0;   // == 1
        const int yC = midx / NCOL;
        const int xC = midx - yC * NCOL;
        const int b  = task / NJOINT;
        const int j  = task - b * NJOINT;
        const float* __restrict__ ob = osp + ((size_t)b * (2 * NJOINT) + j) * NPIX;
        const float osx = ob[midx];
        const float osy = ob[(size_t)NJOINT * NPIX + midx];
        const bool cond = mval > 0.5f;
        const float sc = 1.0f / (float)NCOL;
        const float x0 = cond ? (osx + (float)xC) * sc : 0.f;
        const float x1 = cond ? (osy + (float)yC) * sc : 0.f;
        const float dx = x0 - t0;
        const float dy = x1 - t1;
        d2v = dx * dx + dy * dy;
    }

    // ---- deterministic block reduction (doubles) ----
    sd[tid] = (double)acc + (double)d2v;
    sn[tid] = (double)nv;
    __syncthreads();
    #pragma unroll
    for (int off = BLOCK1 / 2; off > 0; off >>= 1) {
        if (tid < off) {
            sd[tid] += sd[tid + off];
            sn[tid] += sn[tid + off];
        }
        __syncthreads();
    }
    if (tid == 0) {
        partials[blockIdx.x * 2 + 0] = sd[0];
        partials[blockIdx.x * 2 + 1] = sn[0];
    }
}

__global__ __launch_bounds__(256) void mse2_reduce(const double* __restrict__ partials,
                                                   float* __restrict__ out)
{
    __shared__ double ssum[256], snum[256];
    double s = 0.0, n = 0.0;
    for (int i = threadIdx.x; i < GRID1; i += 256) {
        s += partials[i * 2 + 0];
        n += partials[i * 2 + 1];
    }
    ssum[threadIdx.x] = s;
    snum[threadIdx.x] = n;
    __syncthreads();
    for (int off = 128; off; off >>= 1) {
        if (threadIdx.x < off) {
            ssum[threadIdx.x] += ssum[threadIdx.x + off];
            snum[threadIdx.x] += snum[threadIdx.x + off];
        }
        __syncthreads();
    }
    if (threadIdx.x == 0) out[0] = (float)(ssum[0] / snum[0]);
}

extern "C" void kernel_launch(void* const* d_in, const int* in_sizes, int n_in,
                              void* d_out, int out_size, void* d_ws, size_t ws_size,
                              hipStream_t stream) {
    const float* osp = (const float*)d_in[0];
    const float* h   = (const float*)d_in[1];
    // d_in[2] = op, unused by the reference
    const float* t   = (const float*)d_in[3];
    const float* v   = (const float*)d_in[4];
    double* partials = (double*)d_ws;
    float* out = (float*)d_out;

    mse2_main<<<GRID1, BLOCK1, 0, stream>>>(osp, h, t, v, partials);
    mse2_reduce<<<1, 256, 0, stream>>>(partials, out);
}